// Round 2
// baseline (370.667 us; speedup 1.0000x reference)
//
#include <hip/hip_runtime.h>

// ---------------------------------------------------------------------------
// Multiheaded_GRUMix_Attention on MI355X (gfx950). Inputs f32, output f32.
//
// R11: GEMM family unified into gemm128: 128x128 tile, BK=64, m97-class.
//  - B staged via global_load_lds (16B); weight tensors stored PRE-SWIZZLED
//    (k bits[5:3] ^= row&7) by trans_w so linear LDS image + XOR'd ds_read
//    is bank-conflict-free (both-sides-or-neither rule).
//  - A (f32) reg-staged with in-flight bf16 convert, XOR-swizzled LDS write.
//  - split-precision GEMM = same kernel, K'=1536 pointer schedule
//    (AhBh, AhBl, AlBh phases). gemm_out = bf16-A mode; attn stores att
//    pre-swizzled (sole consumer).
//  - LDS-packed epilogues: coalesced 64B/thread stores.
// attn/gru/mix_len unchanged from R10 (attn 79us, single barrier).
// ---------------------------------------------------------------------------

typedef __bf16 bf16;
typedef __bf16 bfx8 __attribute__((ext_vector_type(8)));
typedef float v4f __attribute__((ext_vector_type(4)));

__device__ inline float sigm(float x) { return 1.0f / (1.0f + __expf(-x)); }
__device__ inline float tanh_fast(float x) { return 1.0f - 2.0f / (__expf(2.0f * x) + 1.0f); }

__device__ inline v4f mfma16(bfx8 a, bfx8 b, v4f c) {
    return __builtin_amdgcn_mfma_f32_16x16x32_bf16(a, b, c, 0, 0, 0);
}

typedef const __attribute__((address_space(1))) void* gvp;
typedef __attribute__((address_space(3))) void* lvp;

__device__ inline void gload_lds16(const bf16* g, bf16* l) {
    __builtin_amdgcn_global_load_lds((gvp)g, (lvp)l, 16, 0, 0);
}

__device__ inline void split8(const float* __restrict__ p, bfx8& hi, bfx8& lo) {
    float4 x = *(const float4*)p;
    float4 y = *(const float4*)(p + 4);
    float v[8] = {x.x, x.y, x.z, x.w, y.x, y.y, y.z, y.w};
#pragma unroll
    for (int j = 0; j < 8; ++j) {
        bf16 h = (bf16)v[j];
        hi[j] = h;
        lo[j] = (bf16)(v[j] - (float)h);
    }
}

// ---------------------------------------------------------------------------
// Prep: transpose-convert weights [512][512] f32 -> bf16 W^T[col][k'], with
// k' = k ^ ((col&7)<<3): storage pre-swizzled so gemm128's linear
// global_load_lds image is bank-conflict-free under XOR'd ds_read.
// Optional lo plane (Wpos).
// ---------------------------------------------------------------------------
struct TW { const float* src[5]; bf16* dst[5]; bf16* dstlo[5]; };

__global__ __launch_bounds__(256) void trans_w_kernel(TW a) {
    __shared__ float tile[64][68];
    const float* src = a.src[blockIdx.y];
    bf16* dst = a.dst[blockIdx.y];
    bf16* dlo = a.dstlo[blockIdx.y];
    const int rbase = (blockIdx.x >> 3) * 64, cbase = (blockIdx.x & 7) * 64;
    const int t = threadIdx.x;
    const int r = t >> 2, cc = (t & 3) * 16;
    {
        const float* p = src + (long)(rbase + r) * 512 + cbase + cc;
        *(float4*)(&tile[r][cc]) = *(const float4*)p;
        *(float4*)(&tile[r][cc + 4]) = *(const float4*)(p + 4);
        *(float4*)(&tile[r][cc + 8]) = *(const float4*)(p + 8);
        *(float4*)(&tile[r][cc + 12]) = *(const float4*)(p + 12);
    }
    __syncthreads();
    {
        bfx8 h0, h1, l0, l1;
#pragma unroll
        for (int j = 0; j < 8; ++j) {
            float v0 = tile[cc + j][r];
            float v1 = tile[cc + 8 + j][r];
            bf16 a0 = (bf16)v0, a1 = (bf16)v1;
            h0[j] = a0; l0[j] = (bf16)(v0 - (float)a0);
            h1[j] = a1; l1[j] = (bf16)(v1 - (float)a1);
        }
        const int n_ = cbase + r;                 // output row (weight col)
        const int x_ = (n_ & 7) << 3;             // swizzle of k bits [5:3]
        const long rowo = (long)n_ * 512;
        const int ka = (rbase + cc) ^ x_;
        const int kb = (rbase + cc + 8) ^ x_;
        *(bfx8*)(dst + rowo + ka) = h0;
        *(bfx8*)(dst + rowo + kb) = h1;
        if (dlo) {
            *(bfx8*)(dlo + rowo + ka) = l0;
            *(bfx8*)(dlo + rowo + kb) = l1;
        }
    }
}

// ---------------------------------------------------------------------------
// Prep: GRU weights [64][192] f32 -> split-transposed bf16 [192][64] hi/lo.
// ---------------------------------------------------------------------------
__global__ void gru_prep_kernel(const float* __restrict__ gwi, const float* __restrict__ gwh,
                                bf16* ih, bf16* il, bf16* hh, bf16* hl) {
    const float* src = blockIdx.x ? gwh : gwi;
    bf16* dh = blockIdx.x ? hh : ih;
    bf16* dl = blockIdx.x ? hl : il;
    int n = threadIdx.x;
    for (int k = 0; k < 64; ++k) {
        float v = src[k * 192 + n];
        bf16 h = (bf16)v;
        dh[n * 64 + k] = h;
        dl[n * 64 + k] = (bf16)(v - (float)h);
    }
}

// ---------------------------------------------------------------------------
// Unified 128x128 GEMM. modes:
//  0: C bf16 [M][512]          (Q/K projections)
//  1: C^T bf16 per-n [512][512] (V projection -> VhT)
//  2: split hi/lo + relu+bias   (Xg; K'=1536 schedule AhBh,AhBl,AlBh)
//  3: C f32 [M][512]            (out GEMM; A is pre-swizzled bf16)
// B (and mode3 A) sources are stored pre-swizzled; LDS image is linear;
// ds_read applies chunk' = (ks*4+quad) ^ (row&7). A f32 reg-staged with the
// same swizzle on the LDS write (bank-even).
// ---------------------------------------------------------------------------
struct GEMMDesc {
    const float* Af;
    const bf16* Ab;
    const bf16* B0;
    const bf16* B1;
    const float* bias;
    bf16* Cb;
    bf16* Cl;
    float* Cf;
    int mode;
};
struct G4 { GEMMDesc d[4]; };

__global__ __launch_bounds__(256, 4) void gemm128(G4 gg) {
    __shared__ bf16 sm[16384];   // As = sm[0..8191] [128][64], Bs = sm[8192..]
    bf16* As = sm;
    bf16* Bs = sm + 8192;

    const GEMMDesc g = gg.d[blockIdx.z];
    const int mode = g.mode;
    const int mbase = blockIdx.x * 128, nbase = blockIdx.y * 128;
    const int t = threadIdx.x, w = t >> 6, l = t & 63;
    const int quad = l >> 4, c = l & 15;
    const int wr = w >> 1, wc = w & 1;

    const v4f zero4 = {0.f, 0.f, 0.f, 0.f};
    v4f acc[4][4];
#pragma unroll
    for (int m = 0; m < 4; ++m)
#pragma unroll
        for (int nn = 0; nn < 4; ++nn) acc[m][nn] = zero4;

    const int nsteps = (mode == 2) ? 24 : 8;
    const int arow_t = t >> 3;               // 0..31, row&7 == (t>>3)&7
    const int ach = t & 7;                   // A global chunk
    const int asw = ((ach ^ (arow_t & 7)) * 8);  // swizzled LDS chunk offset
    const int xm = c & 7;                    // frag-read row&7

    for (int s = 0; s < nsteps; ++s) {
        const bf16* Bsrc = g.B0;
        int k0;
        bool lo = false;
        if (mode == 2) {
            int ph = s >> 3;
            k0 = (s & 7) * 64;
            if (ph == 1) Bsrc = g.B1;
            lo = (ph == 2);
        } else {
            k0 = s * 64;
        }

        // ---- stage B: 4x global_load_lds (pre-swizzled source, linear LDS)
#pragma unroll
        for (int j = 0; j < 4; ++j) {
            int slot = w * 4 + j;
            int row = slot * 8 + (l >> 3);
            const bf16* src = Bsrc + (long)(nbase + row) * 512 + k0 + (l & 7) * 8;
            gload_lds16(src, Bs + slot * 512);
        }
        // ---- stage A
        if (mode == 3) {
#pragma unroll
            for (int j = 0; j < 4; ++j) {
                int slot = w * 4 + j;
                int row = slot * 8 + (l >> 3);
                const bf16* src = g.Ab + (long)(mbase + row) * 512 + k0 + (l & 7) * 8;
                gload_lds16(src, As + slot * 512);
            }
        } else {
#pragma unroll
            for (int j = 0; j < 4; ++j) {
                int row = j * 32 + arow_t;
                const float* p = g.Af + (long)(mbase + row) * 512 + k0 + ach * 8;
                float4 x = *(const float4*)p, y = *(const float4*)(p + 4);
                float v[8] = {x.x, x.y, x.z, x.w, y.x, y.y, y.z, y.w};
                bfx8 hv;
                if (!lo) {
#pragma unroll
                    for (int q = 0; q < 8; ++q) hv[q] = (bf16)v[q];
                } else {
#pragma unroll
                    for (int q = 0; q < 8; ++q) {
                        bf16 h = (bf16)v[q];
                        hv[q] = (bf16)(v[q] - (float)h);
                    }
                }
                *(bfx8*)(&As[row * 64 + asw]) = hv;
            }
        }
        __syncthreads();

        // ---- compute: 2 k-substeps x 16 MFMA
#pragma unroll
        for (int ks = 0; ks < 2; ++ks) {
            const int off = (((ks * 4 + quad) ^ xm) * 8);
            bfx8 af[4], bb[4];
#pragma unroll
            for (int m = 0; m < 4; ++m)
                af[m] = *(const bfx8*)(&As[(wr * 64 + m * 16 + c) * 64 + off]);
#pragma unroll
            for (int nn = 0; nn < 4; ++nn)
                bb[nn] = *(const bfx8*)(&Bs[(wc * 64 + nn * 16 + c) * 64 + off]);
#pragma unroll
            for (int m = 0; m < 4; ++m)
#pragma unroll
                for (int nn = 0; nn < 4; ++nn)
                    acc[m][nn] = mfma16(af[m], bb[nn], acc[m][nn]);
        }
        __syncthreads();
    }

    // ---- epilogues
    if (mode == 3) {
        float* C = g.Cf;
#pragma unroll
        for (int m = 0; m < 4; ++m)
#pragma unroll
            for (int nn = 0; nn < 4; ++nn)
#pragma unroll
                for (int i = 0; i < 4; ++i) {
                    int row = mbase + wr * 64 + m * 16 + quad * 4 + i;
                    int col = nbase + wc * 64 + nn * 16 + c;
                    C[(long)row * 512 + col] = acc[m][nn][i];
                }
        return;
    }

    if (mode == 1) {
        // transpose epilogue: C^T[n][col][s]
        bf16* CT = g.Cb + ((long)(mbase >> 9)) * 262144;
        const int s0 = mbase & 511;
        for (int h = 0; h < 2; ++h) {
            if (wr == h) {
#pragma unroll
                for (int m = 0; m < 4; ++m)
#pragma unroll
                    for (int nn = 0; nn < 4; ++nn)
#pragma unroll
                        for (int i = 0; i < 4; ++i)
                            sm[(wc * 64 + nn * 16 + c) * 64 + m * 16 + quad * 4 + i] =
                                (bf16)acc[m][nn][i];
            }
            __syncthreads();
            {
                const bf16* src = sm + (t >> 1) * 64 + (t & 1) * 32;
                bf16* d = CT + (long)(nbase + (t >> 1)) * 512 + s0 + h * 64 + (t & 1) * 32;
#pragma unroll
                for (int j = 0; j < 4; ++j) *(bfx8*)(d + j * 8) = *(const bfx8*)(src + j * 8);
            }
            __syncthreads();
        }
        return;
    }

    // modes 0 / 2: row-major bf16 via LDS pack (coalesced 64B/thread stores)
    for (int h = 0; h < 2; ++h) {
        if (wr == h) {
#pragma unroll
            for (int m = 0; m < 4; ++m)
#pragma unroll
                for (int nn = 0; nn < 4; ++nn)
#pragma unroll
                    for (int i = 0; i < 4; ++i) {
                        int col = wc * 64 + nn * 16 + c;
                        float v = acc[m][nn][i];
                        if (mode == 2) v = fmaxf(v + g.bias[nbase + col], 0.f);
                        bf16 hv = (bf16)v;
                        sm[(m * 16 + quad * 4 + i) * 128 + col] = hv;
                        if (mode == 2)
                            sm[8192 + (m * 16 + quad * 4 + i) * 128 + col] =
                                (bf16)(v - (float)hv);
                    }
        }
        __syncthreads();
        {
            const int row = t >> 2, seg = t & 3;
            const bf16* src = sm + row * 128 + seg * 32;
            bf16* d = g.Cb + (long)(mbase + h * 64 + row) * 512 + nbase + seg * 32;
#pragma unroll
            for (int j = 0; j < 4; ++j) *(bfx8*)(d + j * 8) = *(const bfx8*)(src + j * 8);
            if (mode == 2) {
                const bf16* src2 = sm + 8192 + row * 128 + seg * 32;
                bf16* d2 = g.Cl + (long)(mbase + h * 64 + row) * 512 + nbase + seg * 32;
#pragma unroll
                for (int j = 0; j < 4; ++j) *(bfx8*)(d2 + j * 8) = *(const bfx8*)(src2 + j * 8);
            }
        }
        __syncthreads();
    }
}

// ---------------------------------------------------------------------------
// mix gate + lengths + packed mask bitmasks: one wave per (n,q) row.
// ---------------------------------------------------------------------------
__global__ __launch_bounds__(256) void mix_len_kernel(
    const float* __restrict__ Q, const int* __restrict__ mask,
    const float* __restrict__ mix_w, const float* __restrict__ mix_b,
    float* __restrict__ mixv, float* __restrict__ stepv, float* __restrict__ lenv,
    unsigned* __restrict__ maskbits) {
    int row = blockIdx.x * 4 + (threadIdx.x >> 6);
    int lane = threadIdx.x & 63;
    float dot = 0.f, ms = 0.f;
    unsigned myw = 0;
#pragma unroll
    for (int j = 0; j < 8; ++j) {
        float qv = Q[(long)row * 512 + j * 64 + lane];
        float wv = mix_w[j * 64 + lane];
        dot += qv * wv;
        int mv = mask[(long)row * 512 + j * 64 + lane];
        unsigned long long b = __ballot(mv != 0);
        ms += (float)__popcll(b);
        if ((lane >> 1) == j) myw = (unsigned)(b >> ((lane & 1) * 32));
    }
#pragma unroll
    for (int o = 32; o > 0; o >>= 1) dot += __shfl_xor(dot, o);
    if (lane < 16) maskbits[(long)row * 16 + lane] = myw;
    if (lane == 0) {
        mixv[row] = sigm(dot + mix_b[0]);
        lenv[row] = ms;
        stepv[row] = 1.0f / fmaxf(1.0f, ms - 1.0f);
    }
}

// ---------------------------------------------------------------------------
// Fused GRU: 64 rows/block of one (n,hd); split Xg + split hp; fast tanh.
// ---------------------------------------------------------------------------
__global__ __launch_bounds__(256) void gru_fused_kernel(
    const bf16* __restrict__ Xh, const bf16* __restrict__ Xl,
    const float* __restrict__ hp,
    const bf16* __restrict__ wih, const bf16* __restrict__ wil,
    const bf16* __restrict__ whh, const bf16* __restrict__ whl,
    const float* __restrict__ gbi, const float* __restrict__ gbh,
    const float* __restrict__ pa, const float* __restrict__ Wsigma,
    const float* __restrict__ Wrho,
    const float* __restrict__ lenv, const float* __restrict__ stepv,
    float* __restrict__ muv, float* __restrict__ sigv) {
    __shared__ bf16 Wh[192][72], Wl[192][72];
    __shared__ float biL[384];

    const int b = blockIdx.x;
    const int qb = b & 7, nh = b >> 3, hd = nh & 7, n = nh >> 3;
    const int t = threadIdx.x;
    const int w = t >> 6, lane = t & 63, quad = lane >> 4, c = lane & 15;
    const int q0 = qb * 64 + w * 16;

    if (t < 192) { biL[t] = gbi[t]; biL[192 + t] = gbh[t]; }
#pragma unroll
    for (int it = 0; it < 6; ++it) {
        int task = it * 256 + t;
        int r = task >> 3, ch = task & 7;
        *(bfx8*)(&Wh[r][ch * 8]) = *(const bfx8*)(wih + r * 64 + ch * 8);
        *(bfx8*)(&Wl[r][ch * 8]) = *(const bfx8*)(wil + r * 64 + ch * 8);
    }
    __syncthreads();

    const v4f zero4 = {0.f, 0.f, 0.f, 0.f};
    v4f gi[12], gh[12];
#pragma unroll
    for (int nt = 0; nt < 12; ++nt) gi[nt] = zero4;
#pragma unroll
    for (int ks = 0; ks < 2; ++ks) {
        long ao = (long)(n * 512 + q0 + c) * 512 + hd * 64 + ks * 32 + quad * 8;
        bfx8 xh = *(const bfx8*)(Xh + ao);
        bfx8 xl = *(const bfx8*)(Xl + ao);
#pragma unroll
        for (int nt = 0; nt < 12; ++nt) {
            bfx8 bh = *(const bfx8*)(&Wh[nt * 16 + c][ks * 32 + quad * 8]);
            bfx8 bl = *(const bfx8*)(&Wl[nt * 16 + c][ks * 32 + quad * 8]);
            gi[nt] = mfma16(xh, bh, gi[nt]);
            gi[nt] = mfma16(xh, bl, gi[nt]);
            gi[nt] = mfma16(xl, bh, gi[nt]);
        }
    }
    __syncthreads();
#pragma unroll
    for (int it = 0; it < 6; ++it) {
        int task = it * 256 + t;
        int r = task >> 3, ch = task & 7;
        *(bfx8*)(&Wh[r][ch * 8]) = *(const bfx8*)(whh + r * 64 + ch * 8);
        *(bfx8*)(&Wl[r][ch * 8]) = *(const bfx8*)(whl + r * 64 + ch * 8);
    }
    __syncthreads();
#pragma unroll
    for (int nt = 0; nt < 12; ++nt) gh[nt] = zero4;
#pragma unroll
    for (int ks = 0; ks < 2; ++ks) {
        bfx8 ah, al;
        split8(hp + (long)(nh * 512 + q0 + c) * 64 + ks * 32 + quad * 8, ah, al);
#pragma unroll
        for (int nt = 0; nt < 12; ++nt) {
            bfx8 bh = *(const bfx8*)(&Wh[nt * 16 + c][ks * 32 + quad * 8]);
            bfx8 bl = *(const bfx8*)(&Wl[nt * 16 + c][ks * 32 + quad * 8]);
            gh[nt] = mfma16(ah, bh, gh[nt]);
            gh[nt] = mfma16(ah, bl, gh[nt]);
            gh[nt] = mfma16(al, bh, gh[nt]);
        }
    }

    float st[4][4];
#pragma unroll
    for (int t4 = 0; t4 < 4; ++t4) {
        float bir = biL[t4 * 16 + c];
        float biz = biL[64 + t4 * 16 + c];
        float bin = biL[128 + t4 * 16 + c];
        float bhr = biL[192 + t4 * 16 + c];
        float bhz = biL[256 + t4 * 16 + c];
        float bhn = biL[320 + t4 * 16 + c];
#pragma unroll
        for (int i = 0; i < 4; ++i) {
            int row = q0 + quad * 4 + i;
            float r = sigm(gi[t4][i] + bir + gh[t4][i] + bhr);
            float z = sigm(gi[t4 + 4][i] + biz + gh[t4 + 4][i] + bhz);
            float nn_ = tanh_fast(gi[t4 + 8][i] + bin + r * (gh[t4 + 8][i] + bhn));
            float hpv = hp[(long)(nh * 512 + row) * 64 + t4 * 16 + c];
            st[t4][i] = (1.0f - z) * nn_ + z * hpv;
        }
    }

    float ws_[4], wr0[4], wr1[4], wr2[4];
#pragma unroll
    for (int t4 = 0; t4 < 4; ++t4) {
        int d = t4 * 16 + c;
        ws_[t4] = Wsigma[hd * 64 + d];
        wr0[t4] = Wrho[(hd * 64 + d) * 3 + 0];
        wr1[t4] = Wrho[(hd * 64 + d) * 3 + 1];
        wr2[t4] = Wrho[(hd * 64 + d) * 3 + 2];
    }
#pragma unroll
    for (int i = 0; i < 4; ++i) {
        float s0 = 0.f, s1 = 0.f, s2 = 0.f, s3 = 0.f;
#pragma unroll
        for (int t4 = 0; t4 < 4; ++t4) {
            float sv = st[t4][i];
            s0 += sv * ws_[t4];
            s1 += sv * wr0[t4];
            s2 += sv * wr1[t4];
            s3 += sv * wr2[t4];
        }
#pragma unroll
        for (int o = 1; o < 16; o <<= 1) {
            s0 += __shfl_xor(s0, o);
            s1 += __shfl_xor(s1, o);
            s2 += __shfl_xor(s2, o);
            s3 += __shfl_xor(s3, o);
        }
        if (c == 0) {
            int row = q0 + quad * 4 + i;
            int idx = nh * 512 + row, rq = n * 512 + row;
            float L = lenv[rq], sp = stepv[rq];
            float sg = (fmaxf(s0, 0.f) + 0.27f) / L;
            float fl = floorf(s1);
            float steps = fl + sigm(10.0f * (fabsf(s1 - fl) - 0.5f));
            float ag = sigm(s2), bg = sigm(s3);
            float mu_ = steps * sp + ag * pa[idx] + bg;
            float mu = fmaxf(0.01f * mu_, fminf(mu_, 1.0f + 0.01f * mu_));
            muv[idx] = mu;
            sigv[idx] = sg;
        }
    }
}

// ---------------------------------------------------------------------------
// Fused attention v5 (R10 structure, single barrier). Only change: att is
// stored PRE-SWIZZLED (col bits[5:3] ^= q&7) for gemm128 mode-3 consumption.
// ---------------------------------------------------------------------------
__global__ __launch_bounds__(256) void attn_fused_kernel(
    const bf16* __restrict__ Qh, const bf16* __restrict__ Kh,
    const bf16* __restrict__ VhT, const unsigned* __restrict__ maskbits,
    const float* __restrict__ vpos, const float* __restrict__ mixv,
    const float* __restrict__ stepv, const float* __restrict__ muv,
    const float* __restrict__ sigv, bf16* __restrict__ att) {
    __shared__ bf16 Pp[16][520];
    __shared__ bf16 Pg[16][520];
    __shared__ float rsum[4][16], rgsum[4][16];

    const int b = blockIdx.x;
    const int nh = ((b >> 8) << 3) | (b & 7);
    const int qt = (b >> 3) & 31;
    const int hd = nh & 7, n = nh >> 3;
    const int t = threadIdx.x;
    const int wave = t >> 6, lane = t & 63;
    const int quad = lane >> 4, c = lane & 15;
    const int qloc = quad * 4;

    const bf16* qrow = Qh + (long)(n * 512 + qt * 16 + c) * 512 + hd * 64 + quad * 8;
    bfx8 afr0 = *(const bfx8*)qrow;
    bfx8 afr1 = *(const bfx8*)(qrow + 32);

    const v4f zero4 = {0.f, 0.f, 0.f, 0.f};
    v4f acc[8];
#pragma unroll
    for (int i = 0; i < 8; ++i) acc[i] = zero4;

    const bf16* kbase = Kh + (long)(n * 512 + wave * 128 + c) * 512 + hd * 64 + quad * 8;
#pragma unroll
    for (int t8 = 0; t8 < 8; ++t8) {
        bfx8 b0 = *(const bfx8*)(kbase + (long)t8 * 16 * 512);
        bfx8 b1 = *(const bfx8*)(kbase + (long)t8 * 16 * 512 + 32);
        acc[t8] = mfma16(afr0, b0, acc[t8]);
        acc[t8] = mfma16(afr1, b1, acc[t8]);
    }

    float mu_[4], i2s[4], stp[4];
#pragma unroll
    for (int i = 0; i < 4; ++i) {
        int q = qt * 16 + qloc + i;
        int idx = nh * 512 + q, rq = n * 512 + q;
        mu_[i] = muv[idx];
        float sg = sigv[idx];
        i2s[i] = 0.5f / (sg * sg);
        stp[i] = stepv[rq];
    }

    unsigned mbits[4];
    {
        const unsigned* mrow = maskbits + ((long)(n * 512 + qt * 16) << 4) + wave * 4;
#pragma unroll
        for (int i = 0; i < 4; ++i) {
            const unsigned* mr = mrow + ((qloc + i) << 4);
            unsigned w0 = mr[0], w1 = mr[1], w2 = mr[2], w3 = mr[3];
            mbits[i] = ((w0 >> c) & 1u) | (((w0 >> (16 + c)) & 1u) << 1) |
                       (((w1 >> c) & 1u) << 2) | (((w1 >> (16 + c)) & 1u) << 3) |
                       (((w2 >> c) & 1u) << 4) | (((w2 >> (16 + c)) & 1u) << 5) |
                       (((w3 >> c) & 1u) << 6) | (((w3 >> (16 + c)) & 1u) << 7);
        }
    }

    float vp[8];
#pragma unroll
    for (int t8 = 0; t8 < 8; ++t8) vp[t8] = vpos[wave * 128 + t8 * 16 + c];

    float psum[4] = {0.f, 0.f, 0.f, 0.f};
    float gsum[4] = {0.f, 0.f, 0.f, 0.f};
#pragma unroll
    for (int i = 0; i < 4; ++i) {
        float m = mu_[i], s = stp[i], c2 = i2s[i];
#pragma unroll
        for (int t8 = 0; t8 < 8; ++t8) {
            int on = (mbits[i] >> t8) & 1;
            float pv = on ? __expf(acc[t8][i] * 0.125f) : 0.f;
            float d = vp[t8] * s - m;
            float gv = on ? __expf(-(d * d) * c2) : 0.f;
            psum[i] += pv;
            gsum[i] += gv;
            int k = wave * 128 + t8 * 16 + c;
            Pp[qloc + i][k] = (bf16)pv;
            Pg[qloc + i][k] = (bf16)gv;
        }
    }
#pragma unroll
    for (int i = 0; i < 4; ++i) {
#pragma unroll
        for (int o = 1; o < 16; o <<= 1) {
            psum[i] += __shfl_xor(psum[i], o);
            gsum[i] += __shfl_xor(gsum[i], o);
        }
        if (c == 0) {
            rsum[wave][qloc + i] = psum[i];
            rgsum[wave][qloc + i] = gsum[i];
        }
    }

    __syncthreads();  // the ONLY barrier

    float ac[4], bc[4];
#pragma unroll
    for (int i = 0; i < 4; ++i) {
        float Sp = rsum[0][qloc + i] + rsum[1][qloc + i] + rsum[2][qloc + i] + rsum[3][qloc + i];
        float Sg = rgsum[0][qloc + i] + rgsum[1][qloc + i] + rgsum[2][qloc + i] +
                   rgsum[3][qloc + i] + 512.0f * 1e-20f;
        float m_ = mixv[n * 512 + qt * 16 + qloc + i];
        ac[i] = (1.0f - m_) / Sp;
        bc[i] = m_ / Sg;
    }

    v4f accP = zero4, accG = zero4;
    const bf16* vrow = VhT + (long)(n * 512 + hd * 64 + wave * 16 + c) * 512 + quad * 8;
#pragma unroll
    for (int ks = 0; ks < 16; ++ks) {
        bfx8 bf_ = *(const bfx8*)(vrow + ks * 32);
        bfx8 ap = *(const bfx8*)(&Pp[c][ks * 32 + quad * 8]);
        bfx8 ag = *(const bfx8*)(&Pg[c][ks * 32 + quad * 8]);
        accP = mfma16(ap, bf_, accP);
        accG = mfma16(ag, bf_, accG);
    }

#pragma unroll
    for (int i = 0; i < 4; ++i) {
        int q = qt * 16 + quad * 4 + i;
        int cx = (wave * 16 + c) ^ (((quad * 4 + i) & 7) << 3);  // pre-swizzle for gemm128
        att[(long)(n * 512 + q) * 512 + hd * 64 + cx] =
            (bf16)(ac[i] * accP[i] + bc[i] * accG[i]);
    }
}

// ---------------------------------------------------------------------------
extern "C" void kernel_launch(void* const* d_in, const int* in_sizes, int n_in,
                              void* d_out, int out_size, void* d_ws, size_t ws_size,
                              hipStream_t stream) {
    (void)in_sizes; (void)n_in; (void)out_size; (void)ws_size;

    const float* Q = (const float*)d_in[0];
    const float* K = (const float*)d_in[1];
    const float* V = (const float*)d_in[2];
    const float* past_state = (const float*)d_in[3];
    const float* past_att = (const float*)d_in[4];
    const float* vpos = (const float*)d_in[5];
    const int* mask = (const int*)d_in[6];
    const float* Wq = (const float*)d_in[7];
    const float* Wk = (const float*)d_in[8];
    const float* Wv = (const float*)d_in[9];
    const float* Wpos = (const float*)d_in[10];
    const float* bpos = (const float*)d_in[11];
    const float* Wsigma = (const float*)d_in[12];
    const float* Wrho = (const float*)d_in[13];
    const float* mix_w = (const float*)d_in[14];
    const float* mix_b = (const float*)d_in[15];
    const float* gwi = (const float*)d_in[16];
    const float* gwh = (const float*)d_in[17];
    const float* gbi = (const float*)d_in[18];
    const float* gbh = (const float*)d_in[19];
    const float* Wc = (const float*)d_in[20];
    float* out = (float*)d_out;

    // ---- workspace ----
    char* p = (char*)d_ws;
    const size_t SZB = 8192UL * 512 * 2;
    const size_t SZW = 512UL * 512 * 2;
    bf16* WqT = (bf16*)p;   p += SZW;
    bf16* WkT = (bf16*)p;   p += SZW;
    bf16* WvT = (bf16*)p;   p += SZW;
    bf16* WpT = (bf16*)p;   p += SZW;
    bf16* WpTl = (bf16*)p;  p += SZW;
    bf16* WcT = (bf16*)p;   p += SZW;
    bf16* wih = (bf16*)p;   p += 24576;
    bf16* wil = (bf16*)p;   p += 24576;
    bf16* whh = (bf16*)p;   p += 24576;
    bf16* whl = (bf16*)p;   p += 24576;
    bf16* Qh = (bf16*)p;    p += SZB;
    bf16* Kh = (bf16*)p;    p += SZB;
    bf16* VhT = (bf16*)p;   p += SZB;
    bf16* Xh = (bf16*)p;
    bf16* att = Xh;         p += SZB;
    bf16* Xl = (bf16*)p;    p += SZB;
    unsigned* maskbits = (unsigned*)p;   p += 8192UL * 16 * 4;
    float* mixv = (float*)p;  p += 32768;
    float* stepv = (float*)p; p += 32768;
    float* lenv = (float*)p;  p += 32768;
    float* muv = (float*)p;   p += 262144;
    float* sigv = (float*)p;  p += 262144;

    dim3 blk(256);

    TW tw;
    tw.src[0] = Wq; tw.src[1] = Wk; tw.src[2] = Wv; tw.src[3] = Wpos; tw.src[4] = Wc;
    tw.dst[0] = WqT; tw.dst[1] = WkT; tw.dst[2] = WvT; tw.dst[3] = WpT; tw.dst[4] = WcT;
    tw.dstlo[0] = nullptr; tw.dstlo[1] = nullptr; tw.dstlo[2] = nullptr;
    tw.dstlo[3] = WpTl; tw.dstlo[4] = nullptr;
    trans_w_kernel<<<dim3(64, 5), blk, 0, stream>>>(tw);

    gru_prep_kernel<<<dim3(2), dim3(192), 0, stream>>>(gwi, gwh, wih, wil, whh, whl);

    mix_len_kernel<<<dim3(2048), blk, 0, stream>>>(Q, mask, mix_w, mix_b, mixv, stepv, lenv, maskbits);

    // projections: d[0]=split (longest, launch first), d[1]=Q, d[2]=K, d[3]=V(transposed)
    G4 gp;
    gp.d[0].Af = Q;  gp.d[0].Ab = nullptr; gp.d[0].B0 = WpT; gp.d[0].B1 = WpTl;
    gp.d[0].bias = bpos; gp.d[0].Cb = Xh; gp.d[0].Cl = Xl; gp.d[0].Cf = nullptr; gp.d[0].mode = 2;
    gp.d[1].Af = Q;  gp.d[1].Ab = nullptr; gp.d[1].B0 = WqT; gp.d[1].B1 = nullptr;
    gp.d[1].bias = nullptr; gp.d[1].Cb = Qh; gp.d[1].Cl = nullptr; gp.d[1].Cf = nullptr; gp.d[1].mode = 0;
    gp.d[2].Af = K;  gp.d[2].Ab = nullptr; gp.d[2].B0 = WkT; gp.d[2].B1 = nullptr;
    gp.d[2].bias = nullptr; gp.d[2].Cb = Kh; gp.d[2].Cl = nullptr; gp.d[2].Cf = nullptr; gp.d[2].mode = 0;
    gp.d[3].Af = V;  gp.d[3].Ab = nullptr; gp.d[3].B0 = WvT; gp.d[3].B1 = nullptr;
    gp.d[3].bias = nullptr; gp.d[3].Cb = VhT; gp.d[3].Cl = nullptr; gp.d[3].Cf = nullptr; gp.d[3].mode = 1;
    gemm128<<<dim3(64, 4, 4), blk, 0, stream>>>(gp);

    gru_fused_kernel<<<dim3(1024), blk, 0, stream>>>(
        Xh, Xl, past_state, wih, wil, whh, whl, gbi, gbh, past_att, Wsigma, Wrho,
        lenv, stepv, muv, sigv);

    attn_fused_kernel<<<dim3(4096), blk, 0, stream>>>(
        Qh, Kh, VhT, maskbits, vpos, mixv, stepv, muv, sigv, att);

    G4 go;
    go.d[0].Af = nullptr; go.d[0].Ab = att; go.d[0].B0 = WcT; go.d[0].B1 = nullptr;
    go.d[0].bias = nullptr; go.d[0].Cb = nullptr; go.d[0].Cl = nullptr; go.d[0].Cf = out;
    go.d[0].mode = 3;
    go.d[1] = go.d[0]; go.d[2] = go.d[0]; go.d[3] = go.d[0];  // unused
    gemm128<<<dim3(64, 4, 1), blk, 0, stream>>>(go);
}

// Round 3
// 338.116 us; speedup vs baseline: 1.0963x; 1.0963x over previous
//
#include <hip/hip_runtime.h>

// ---------------------------------------------------------------------------
// Multiheaded_GRUMix_Attention on MI355X (gfx950). Inputs f32, output f32.
//
// R12: gemm128 rebuilt as 2-phase double-buffered pipeline (fixes R11's
// serial issue->drain->compute structure that left MfmaUtil at 10%):
//   - LDS 2x(As 16K + Bs 16K) = 64 KB, 2 blocks/CU
//   - per step: issue s+1 loads (B: global_load_lds -> buf^1, A: f32->regs)
//     BEFORE computing step s from buf[cur]; cvt+ds_write A after the MFMAs
//     (its waitcnt overlaps compute); ONE barrier per step.
//   - global-load latency now lands under the 32-MFMA compute phase.
// Swizzle scheme (pre-swizzled weights/att storage, XOR'd ds_read) unchanged.
// attn (79us single-barrier), gru, mix_len unchanged.
// ---------------------------------------------------------------------------

typedef __bf16 bf16;
typedef __bf16 bfx8 __attribute__((ext_vector_type(8)));
typedef float v4f __attribute__((ext_vector_type(4)));

__device__ inline float sigm(float x) { return 1.0f / (1.0f + __expf(-x)); }
__device__ inline float tanh_fast(float x) { return 1.0f - 2.0f / (__expf(2.0f * x) + 1.0f); }

__device__ inline v4f mfma16(bfx8 a, bfx8 b, v4f c) {
    return __builtin_amdgcn_mfma_f32_16x16x32_bf16(a, b, c, 0, 0, 0);
}

typedef const __attribute__((address_space(1))) void* gvp;
typedef __attribute__((address_space(3))) void* lvp;

__device__ inline void gload_lds16(const bf16* g, bf16* l) {
    __builtin_amdgcn_global_load_lds((gvp)g, (lvp)l, 16, 0, 0);
}

__device__ inline void split8(const float* __restrict__ p, bfx8& hi, bfx8& lo) {
    float4 x = *(const float4*)p;
    float4 y = *(const float4*)(p + 4);
    float v[8] = {x.x, x.y, x.z, x.w, y.x, y.y, y.z, y.w};
#pragma unroll
    for (int j = 0; j < 8; ++j) {
        bf16 h = (bf16)v[j];
        hi[j] = h;
        lo[j] = (bf16)(v[j] - (float)h);
    }
}

// ---------------------------------------------------------------------------
// Prep: transpose-convert weights [512][512] f32 -> bf16 W^T[col][k'], with
// k' = k ^ ((col&7)<<3): storage pre-swizzled so gemm128's linear
// global_load_lds image is bank-conflict-free under XOR'd ds_read.
// Optional lo plane (Wpos).
// ---------------------------------------------------------------------------
struct TW { const float* src[5]; bf16* dst[5]; bf16* dstlo[5]; };

__global__ __launch_bounds__(256) void trans_w_kernel(TW a) {
    __shared__ float tile[64][68];
    const float* src = a.src[blockIdx.y];
    bf16* dst = a.dst[blockIdx.y];
    bf16* dlo = a.dstlo[blockIdx.y];
    const int rbase = (blockIdx.x >> 3) * 64, cbase = (blockIdx.x & 7) * 64;
    const int t = threadIdx.x;
    const int r = t >> 2, cc = (t & 3) * 16;
    {
        const float* p = src + (long)(rbase + r) * 512 + cbase + cc;
        *(float4*)(&tile[r][cc]) = *(const float4*)p;
        *(float4*)(&tile[r][cc + 4]) = *(const float4*)(p + 4);
        *(float4*)(&tile[r][cc + 8]) = *(const float4*)(p + 8);
        *(float4*)(&tile[r][cc + 12]) = *(const float4*)(p + 12);
    }
    __syncthreads();
    {
        bfx8 h0, h1, l0, l1;
#pragma unroll
        for (int j = 0; j < 8; ++j) {
            float v0 = tile[cc + j][r];
            float v1 = tile[cc + 8 + j][r];
            bf16 a0 = (bf16)v0, a1 = (bf16)v1;
            h0[j] = a0; l0[j] = (bf16)(v0 - (float)a0);
            h1[j] = a1; l1[j] = (bf16)(v1 - (float)a1);
        }
        const int n_ = cbase + r;                 // output row (weight col)
        const int x_ = (n_ & 7) << 3;             // swizzle of k bits [5:3]
        const long rowo = (long)n_ * 512;
        const int ka = (rbase + cc) ^ x_;
        const int kb = (rbase + cc + 8) ^ x_;
        *(bfx8*)(dst + rowo + ka) = h0;
        *(bfx8*)(dst + rowo + kb) = h1;
        if (dlo) {
            *(bfx8*)(dlo + rowo + ka) = l0;
            *(bfx8*)(dlo + rowo + kb) = l1;
        }
    }
}

// ---------------------------------------------------------------------------
// Prep: GRU weights [64][192] f32 -> split-transposed bf16 [192][64] hi/lo.
// ---------------------------------------------------------------------------
__global__ void gru_prep_kernel(const float* __restrict__ gwi, const float* __restrict__ gwh,
                                bf16* ih, bf16* il, bf16* hh, bf16* hl) {
    const float* src = blockIdx.x ? gwh : gwi;
    bf16* dh = blockIdx.x ? hh : ih;
    bf16* dl = blockIdx.x ? hl : il;
    int n = threadIdx.x;
    for (int k = 0; k < 64; ++k) {
        float v = src[k * 192 + n];
        bf16 h = (bf16)v;
        dh[n * 64 + k] = h;
        dl[n * 64 + k] = (bf16)(v - (float)h);
    }
}

// ---------------------------------------------------------------------------
// Unified 128x128 GEMM, 2-phase double-buffered. modes:
//  0: C bf16 [M][512]          (Q/K projections)
//  1: C^T bf16 per-n [512][512] (V projection -> VhT)
//  2: split hi/lo + relu+bias   (Xg; K'=1536 schedule AhBh,AhBl,AlBh)
//  3: C f32 [M][512]            (out GEMM; A is pre-swizzled bf16, gload_lds)
// ---------------------------------------------------------------------------
struct GEMMDesc {
    const float* Af;
    const bf16* Ab;
    const bf16* B0;
    const bf16* B1;
    const float* bias;
    bf16* Cb;
    bf16* Cl;
    float* Cf;
    int mode;
};
struct G4 { GEMMDesc d[4]; };

__global__ __launch_bounds__(256, 2) void gemm128(G4 gg) {
    __shared__ bf16 sm[32768];   // 2 bufs x (As[128][64] | Bs[128][64])

    const GEMMDesc g = gg.d[blockIdx.z];
    const int mode = g.mode;
    const int mbase = blockIdx.x * 128, nbase = blockIdx.y * 128;
    const int t = threadIdx.x, w = t >> 6, l = t & 63;
    const int quad = l >> 4, c = l & 15;
    const int wr = w >> 1, wc = w & 1;

    const v4f zero4 = {0.f, 0.f, 0.f, 0.f};
    v4f acc[4][4];
#pragma unroll
    for (int m = 0; m < 4; ++m)
#pragma unroll
        for (int nn = 0; nn < 4; ++nn) acc[m][nn] = zero4;

    const int nsteps = (mode == 2) ? 24 : 8;
    const int arow_t = t >> 3;                    // 0..31
    const int ach = t & 7;
    const int asw = ((ach ^ (arow_t & 7)) * 8);   // swizzled LDS chunk offset
    const int xm = c & 7;
    const int slot0 = w * 4;
    const int srow = l >> 3;                      // 0..7
    const int sch8 = (l & 7) * 8;

    float4 ax[4], ay[4];                          // A f32 prefetch regs

    // ---- issue loads for step s into buffer (As,Bs): B via gload_lds,
    //      A (modes 0/1/2) into registers, A (mode 3) via gload_lds.
    auto issue = [&](int s, bf16* As, bf16* Bs) {
        const bf16* Bsrc = g.B0;
        int k0;
        if (mode == 2) {
            int ph = s >> 3;
            k0 = (s & 7) * 64;
            if (ph == 1) Bsrc = g.B1;
        } else {
            k0 = s * 64;
        }
#pragma unroll
        for (int j = 0; j < 4; ++j) {
            int sl = slot0 + j;
            int row = sl * 8 + srow;
            gload_lds16(Bsrc + (long)(nbase + row) * 512 + k0 + sch8, Bs + sl * 512);
        }
        if (mode == 3) {
#pragma unroll
            for (int j = 0; j < 4; ++j) {
                int sl = slot0 + j;
                int row = sl * 8 + srow;
                gload_lds16(g.Ab + (long)(mbase + row) * 512 + k0 + sch8, As + sl * 512);
            }
        } else {
#pragma unroll
            for (int j = 0; j < 4; ++j) {
                const float* p = g.Af + (long)(mbase + j * 32 + arow_t) * 512 + k0 + ach * 8;
                ax[j] = *(const float4*)p;
                ay[j] = *(const float4*)(p + 4);
            }
        }
    };

    // ---- convert + write prefetched A regs into As (swizzled, linear-bank)
    auto writeA = [&](int s, bf16* As) {
        if (mode == 3) return;
        const bool lo = (mode == 2) && ((s >> 3) == 2);
#pragma unroll
        for (int j = 0; j < 4; ++j) {
            float v[8] = {ax[j].x, ax[j].y, ax[j].z, ax[j].w,
                          ay[j].x, ay[j].y, ay[j].z, ay[j].w};
            bfx8 hv;
            if (!lo) {
#pragma unroll
                for (int q = 0; q < 8; ++q) hv[q] = (bf16)v[q];
            } else {
#pragma unroll
                for (int q = 0; q < 8; ++q) {
                    bf16 h = (bf16)v[q];
                    hv[q] = (bf16)(v[q] - (float)h);
                }
            }
            *(bfx8*)(&As[(j * 32 + arow_t) * 64 + asw]) = hv;
        }
    };

    auto compute = [&](const bf16* As, const bf16* Bs) {
#pragma unroll
        for (int ks = 0; ks < 2; ++ks) {
            const int off = (((ks * 4 + quad) ^ xm) * 8);
            bfx8 af[4], bb[4];
#pragma unroll
            for (int m = 0; m < 4; ++m)
                af[m] = *(const bfx8*)(&As[(wr * 64 + m * 16 + c) * 64 + off]);
#pragma unroll
            for (int nn = 0; nn < 4; ++nn)
                bb[nn] = *(const bfx8*)(&Bs[(wc * 64 + nn * 16 + c) * 64 + off]);
#pragma unroll
            for (int m = 0; m < 4; ++m)
#pragma unroll
                for (int nn = 0; nn < 4; ++nn)
                    acc[m][nn] = mfma16(af[m], bb[nn], acc[m][nn]);
        }
    };

    // ---- pipeline: stage s+1 before computing s; one barrier per step.
    issue(0, sm, sm + 8192);
    writeA(0, sm);
    __syncthreads();
    for (int s = 0; s < nsteps; ++s) {
        bf16* Ac = sm + (s & 1) * 16384;
        bf16* An = sm + (((s & 1) ^ 1) * 16384);
        const bool more = (s + 1 < nsteps);
        if (more) issue(s + 1, An, An + 8192);
        compute(Ac, Ac + 8192);
        if (more) writeA(s + 1, An);
        __syncthreads();
    }

    // ---- epilogues
    if (mode == 3) {
        float* C = g.Cf;
#pragma unroll
        for (int m = 0; m < 4; ++m)
#pragma unroll
            for (int nn = 0; nn < 4; ++nn)
#pragma unroll
                for (int i = 0; i < 4; ++i) {
                    int row = mbase + wr * 64 + m * 16 + quad * 4 + i;
                    int col = nbase + wc * 64 + nn * 16 + c;
                    C[(long)row * 512 + col] = acc[m][nn][i];
                }
        return;
    }

    if (mode == 1) {
        // transpose epilogue: C^T[n][col][s]
        bf16* CT = g.Cb + ((long)(mbase >> 9)) * 262144;
        const int s0 = mbase & 511;
        for (int h = 0; h < 2; ++h) {
            if (wr == h) {
#pragma unroll
                for (int m = 0; m < 4; ++m)
#pragma unroll
                    for (int nn = 0; nn < 4; ++nn)
#pragma unroll
                        for (int i = 0; i < 4; ++i)
                            sm[(wc * 64 + nn * 16 + c) * 64 + m * 16 + quad * 4 + i] =
                                (bf16)acc[m][nn][i];
            }
            __syncthreads();
            {
                const bf16* src = sm + (t >> 1) * 64 + (t & 1) * 32;
                bf16* d = CT + (long)(nbase + (t >> 1)) * 512 + s0 + h * 64 + (t & 1) * 32;
#pragma unroll
                for (int j = 0; j < 4; ++j) *(bfx8*)(d + j * 8) = *(const bfx8*)(src + j * 8);
            }
            __syncthreads();
        }
        return;
    }

    // modes 0 / 2: row-major bf16 via LDS pack (coalesced 64B/thread stores)
    for (int h = 0; h < 2; ++h) {
        if (wr == h) {
#pragma unroll
            for (int m = 0; m < 4; ++m)
#pragma unroll
                for (int nn = 0; nn < 4; ++nn)
#pragma unroll
                    for (int i = 0; i < 4; ++i) {
                        int col = wc * 64 + nn * 16 + c;
                        float v = acc[m][nn][i];
                        if (mode == 2) v = fmaxf(v + g.bias[nbase + col], 0.f);
                        bf16 hv = (bf16)v;
                        sm[(m * 16 + quad * 4 + i) * 128 + col] = hv;
                        if (mode == 2)
                            sm[8192 + (m * 16 + quad * 4 + i) * 128 + col] =
                                (bf16)(v - (float)hv);
                    }
        }
        __syncthreads();
        {
            const int row = t >> 2, seg = t & 3;
            const bf16* src = sm + row * 128 + seg * 32;
            bf16* d = g.Cb + (long)(mbase + h * 64 + row) * 512 + nbase + seg * 32;
#pragma unroll
            for (int j = 0; j < 4; ++j) *(bfx8*)(d + j * 8) = *(const bfx8*)(src + j * 8);
            if (mode == 2) {
                const bf16* src2 = sm + 8192 + row * 128 + seg * 32;
                bf16* d2 = g.Cl + (long)(mbase + h * 64 + row) * 512 + nbase + seg * 32;
#pragma unroll
                for (int j = 0; j < 4; ++j) *(bfx8*)(d2 + j * 8) = *(const bfx8*)(src2 + j * 8);
            }
        }
        __syncthreads();
    }
}

// ---------------------------------------------------------------------------
// mix gate + lengths + packed mask bitmasks: one wave per (n,q) row.
// ---------------------------------------------------------------------------
__global__ __launch_bounds__(256) void mix_len_kernel(
    const float* __restrict__ Q, const int* __restrict__ mask,
    const float* __restrict__ mix_w, const float* __restrict__ mix_b,
    float* __restrict__ mixv, float* __restrict__ stepv, float* __restrict__ lenv,
    unsigned* __restrict__ maskbits) {
    int row = blockIdx.x * 4 + (threadIdx.x >> 6);
    int lane = threadIdx.x & 63;
    float dot = 0.f, ms = 0.f;
    unsigned myw = 0;
#pragma unroll
    for (int j = 0; j < 8; ++j) {
        float qv = Q[(long)row * 512 + j * 64 + lane];
        float wv = mix_w[j * 64 + lane];
        dot += qv * wv;
        int mv = mask[(long)row * 512 + j * 64 + lane];
        unsigned long long b = __ballot(mv != 0);
        ms += (float)__popcll(b);
        if ((lane >> 1) == j) myw = (unsigned)(b >> ((lane & 1) * 32));
    }
#pragma unroll
    for (int o = 32; o > 0; o >>= 1) dot += __shfl_xor(dot, o);
    if (lane < 16) maskbits[(long)row * 16 + lane] = myw;
    if (lane == 0) {
        mixv[row] = sigm(dot + mix_b[0]);
        lenv[row] = ms;
        stepv[row] = 1.0f / fmaxf(1.0f, ms - 1.0f);
    }
}

// ---------------------------------------------------------------------------
// Fused GRU: 64 rows/block of one (n,hd); split Xg + split hp; fast tanh.
// ---------------------------------------------------------------------------
__global__ __launch_bounds__(256) void gru_fused_kernel(
    const bf16* __restrict__ Xh, const bf16* __restrict__ Xl,
    const float* __restrict__ hp,
    const bf16* __restrict__ wih, const bf16* __restrict__ wil,
    const bf16* __restrict__ whh, const bf16* __restrict__ whl,
    const float* __restrict__ gbi, const float* __restrict__ gbh,
    const float* __restrict__ pa, const float* __restrict__ Wsigma,
    const float* __restrict__ Wrho,
    const float* __restrict__ lenv, const float* __restrict__ stepv,
    float* __restrict__ muv, float* __restrict__ sigv) {
    __shared__ bf16 Wh[192][72], Wl[192][72];
    __shared__ float biL[384];

    const int b = blockIdx.x;
    const int qb = b & 7, nh = b >> 3, hd = nh & 7, n = nh >> 3;
    const int t = threadIdx.x;
    const int w = t >> 6, lane = t & 63, quad = lane >> 4, c = lane & 15;
    const int q0 = qb * 64 + w * 16;

    if (t < 192) { biL[t] = gbi[t]; biL[192 + t] = gbh[t]; }
#pragma unroll
    for (int it = 0; it < 6; ++it) {
        int task = it * 256 + t;
        int r = task >> 3, ch = task & 7;
        *(bfx8*)(&Wh[r][ch * 8]) = *(const bfx8*)(wih + r * 64 + ch * 8);
        *(bfx8*)(&Wl[r][ch * 8]) = *(const bfx8*)(wil + r * 64 + ch * 8);
    }
    __syncthreads();

    const v4f zero4 = {0.f, 0.f, 0.f, 0.f};
    v4f gi[12], gh[12];
#pragma unroll
    for (int nt = 0; nt < 12; ++nt) gi[nt] = zero4;
#pragma unroll
    for (int ks = 0; ks < 2; ++ks) {
        long ao = (long)(n * 512 + q0 + c) * 512 + hd * 64 + ks * 32 + quad * 8;
        bfx8 xh = *(const bfx8*)(Xh + ao);
        bfx8 xl = *(const bfx8*)(Xl + ao);
#pragma unroll
        for (int nt = 0; nt < 12; ++nt) {
            bfx8 bh = *(const bfx8*)(&Wh[nt * 16 + c][ks * 32 + quad * 8]);
            bfx8 bl = *(const bfx8*)(&Wl[nt * 16 + c][ks * 32 + quad * 8]);
            gi[nt] = mfma16(xh, bh, gi[nt]);
            gi[nt] = mfma16(xh, bl, gi[nt]);
            gi[nt] = mfma16(xl, bh, gi[nt]);
        }
    }
    __syncthreads();
#pragma unroll
    for (int it = 0; it < 6; ++it) {
        int task = it * 256 + t;
        int r = task >> 3, ch = task & 7;
        *(bfx8*)(&Wh[r][ch * 8]) = *(const bfx8*)(whh + r * 64 + ch * 8);
        *(bfx8*)(&Wl[r][ch * 8]) = *(const bfx8*)(whl + r * 64 + ch * 8);
    }
    __syncthreads();
#pragma unroll
    for (int nt = 0; nt < 12; ++nt) gh[nt] = zero4;
#pragma unroll
    for (int ks = 0; ks < 2; ++ks) {
        bfx8 ah, al;
        split8(hp + (long)(nh * 512 + q0 + c) * 64 + ks * 32 + quad * 8, ah, al);
#pragma unroll
        for (int nt = 0; nt < 12; ++nt) {
            bfx8 bh = *(const bfx8*)(&Wh[nt * 16 + c][ks * 32 + quad * 8]);
            bfx8 bl = *(const bfx8*)(&Wl[nt * 16 + c][ks * 32 + quad * 8]);
            gh[nt] = mfma16(ah, bh, gh[nt]);
            gh[nt] = mfma16(ah, bl, gh[nt]);
            gh[nt] = mfma16(al, bh, gh[nt]);
        }
    }

    float st[4][4];
#pragma unroll
    for (int t4 = 0; t4 < 4; ++t4) {
        float bir = biL[t4 * 16 + c];
        float biz = biL[64 + t4 * 16 + c];
        float bin = biL[128 + t4 * 16 + c];
        float bhr = biL[192 + t4 * 16 + c];
        float bhz = biL[256 + t4 * 16 + c];
        float bhn = biL[320 + t4 * 16 + c];
#pragma unroll
        for (int i = 0; i < 4; ++i) {
            int row = q0 + quad * 4 + i;
            float r = sigm(gi[t4][i] + bir + gh[t4][i] + bhr);
            float z = sigm(gi[t4 + 4][i] + biz + gh[t4 + 4][i] + bhz);
            float nn_ = tanh_fast(gi[t4 + 8][i] + bin + r * (gh[t4 + 8][i] + bhn));
            float hpv = hp[(long)(nh * 512 + row) * 64 + t4 * 16 + c];
            st[t4][i] = (1.0f - z) * nn_ + z * hpv;
        }
    }

    float ws_[4], wr0[4], wr1[4], wr2[4];
#pragma unroll
    for (int t4 = 0; t4 < 4; ++t4) {
        int d = t4 * 16 + c;
        ws_[t4] = Wsigma[hd * 64 + d];
        wr0[t4] = Wrho[(hd * 64 + d) * 3 + 0];
        wr1[t4] = Wrho[(hd * 64 + d) * 3 + 1];
        wr2[t4] = Wrho[(hd * 64 + d) * 3 + 2];
    }
#pragma unroll
    for (int i = 0; i < 4; ++i) {
        float s0 = 0.f, s1 = 0.f, s2 = 0.f, s3 = 0.f;
#pragma unroll
        for (int t4 = 0; t4 < 4; ++t4) {
            float sv = st[t4][i];
            s0 += sv * ws_[t4];
            s1 += sv * wr0[t4];
            s2 += sv * wr1[t4];
            s3 += sv * wr2[t4];
        }
#pragma unroll
        for (int o = 1; o < 16; o <<= 1) {
            s0 += __shfl_xor(s0, o);
            s1 += __shfl_xor(s1, o);
            s2 += __shfl_xor(s2, o);
            s3 += __shfl_xor(s3, o);
        }
        if (c == 0) {
            int row = q0 + quad * 4 + i;
            int idx = nh * 512 + row, rq = n * 512 + row;
            float L = lenv[rq], sp = stepv[rq];
            float sg = (fmaxf(s0, 0.f) + 0.27f) / L;
            float fl = floorf(s1);
            float steps = fl + sigm(10.0f * (fabsf(s1 - fl) - 0.5f));
            float ag = sigm(s2), bg = sigm(s3);
            float mu_ = steps * sp + ag * pa[idx] + bg;
            float mu = fmaxf(0.01f * mu_, fminf(mu_, 1.0f + 0.01f * mu_));
            muv[idx] = mu;
            sigv[idx] = sg;
        }
    }
}

// ---------------------------------------------------------------------------
// Fused attention v5 (single barrier). att stored PRE-SWIZZLED
// (col bits[5:3] ^= q&7) for gemm128 mode-3 consumption.
// ---------------------------------------------------------------------------
__global__ __launch_bounds__(256) void attn_fused_kernel(
    const bf16* __restrict__ Qh, const bf16* __restrict__ Kh,
    const bf16* __restrict__ VhT, const unsigned* __restrict__ maskbits,
    const float* __restrict__ vpos, const float* __restrict__ mixv,
    const float* __restrict__ stepv, const float* __restrict__ muv,
    const float* __restrict__ sigv, bf16* __restrict__ att) {
    __shared__ bf16 Pp[16][520];
    __shared__ bf16 Pg[16][520];
    __shared__ float rsum[4][16], rgsum[4][16];

    const int b = blockIdx.x;
    const int nh = ((b >> 8) << 3) | (b & 7);
    const int qt = (b >> 3) & 31;
    const int hd = nh & 7, n = nh >> 3;
    const int t = threadIdx.x;
    const int wave = t >> 6, lane = t & 63;
    const int quad = lane >> 4, c = lane & 15;
    const int qloc = quad * 4;

    const bf16* qrow = Qh + (long)(n * 512 + qt * 16 + c) * 512 + hd * 64 + quad * 8;
    bfx8 afr0 = *(const bfx8*)qrow;
    bfx8 afr1 = *(const bfx8*)(qrow + 32);

    const v4f zero4 = {0.f, 0.f, 0.f, 0.f};
    v4f acc[8];
#pragma unroll
    for (int i = 0; i < 8; ++i) acc[i] = zero4;

    const bf16* kbase = Kh + (long)(n * 512 + wave * 128 + c) * 512 + hd * 64 + quad * 8;
#pragma unroll
    for (int t8 = 0; t8 < 8; ++t8) {
        bfx8 b0 = *(const bfx8*)(kbase + (long)t8 * 16 * 512);
        bfx8 b1 = *(const bfx8*)(kbase + (long)t8 * 16 * 512 + 32);
        acc[t8] = mfma16(afr0, b0, acc[t8]);
        acc[t8] = mfma16(afr1, b1, acc[t8]);
    }

    float mu_[4], i2s[4], stp[4];
#pragma unroll
    for (int i = 0; i < 4; ++i) {
        int q = qt * 16 + qloc + i;
        int idx = nh * 512 + q, rq = n * 512 + q;
        mu_[i] = muv[idx];
        float sg = sigv[idx];
        i2s[i] = 0.5f / (sg * sg);
        stp[i] = stepv[rq];
    }

    unsigned mbits[4];
    {
        const unsigned* mrow = maskbits + ((long)(n * 512 + qt * 16) << 4) + wave * 4;
#pragma unroll
        for (int i = 0; i < 4; ++i) {
            const unsigned* mr = mrow + ((qloc + i) << 4);
            unsigned w0 = mr[0], w1 = mr[1], w2 = mr[2], w3 = mr[3];
            mbits[i] = ((w0 >> c) & 1u) | (((w0 >> (16 + c)) & 1u) << 1) |
                       (((w1 >> c) & 1u) << 2) | (((w1 >> (16 + c)) & 1u) << 3) |
                       (((w2 >> c) & 1u) << 4) | (((w2 >> (16 + c)) & 1u) << 5) |
                       (((w3 >> c) & 1u) << 6) | (((w3 >> (16 + c)) & 1u) << 7);
        }
    }

    float vp[8];
#pragma unroll
    for (int t8 = 0; t8 < 8; ++t8) vp[t8] = vpos[wave * 128 + t8 * 16 + c];

    float psum[4] = {0.f, 0.f, 0.f, 0.f};
    float gsum[4] = {0.f, 0.f, 0.f, 0.f};
#pragma unroll
    for (int i = 0; i < 4; ++i) {
        float m = mu_[i], s = stp[i], c2 = i2s[i];
#pragma unroll
        for (int t8 = 0; t8 < 8; ++t8) {
            int on = (mbits[i] >> t8) & 1;
            float pv = on ? __expf(acc[t8][i] * 0.125f) : 0.f;
            float d = vp[t8] * s - m;
            float gv = on ? __expf(-(d * d) * c2) : 0.f;
            psum[i] += pv;
            gsum[i] += gv;
            int k = wave * 128 + t8 * 16 + c;
            Pp[qloc + i][k] = (bf16)pv;
            Pg[qloc + i][k] = (bf16)gv;
        }
    }
#pragma unroll
    for (int i = 0; i < 4; ++i) {
#pragma unroll
        for (int o = 1; o < 16; o <<= 1) {
            psum[i] += __shfl_xor(psum[i], o);
            gsum[i] += __shfl_xor(gsum[i], o);
        }
        if (c == 0) {
            rsum[wave][qloc + i] = psum[i];
            rgsum[wave][qloc + i] = gsum[i];
        }
    }

    __syncthreads();  // the ONLY barrier

    float ac[4], bc[4];
#pragma unroll
    for (int i = 0; i < 4; ++i) {
        float Sp = rsum[0][qloc + i] + rsum[1][qloc + i] + rsum[2][qloc + i] + rsum[3][qloc + i];
        float Sg = rgsum[0][qloc + i] + rgsum[1][qloc + i] + rgsum[2][qloc + i] +
                   rgsum[3][qloc + i] + 512.0f * 1e-20f;
        float m_ = mixv[n * 512 + qt * 16 + qloc + i];
        ac[i] = (1.0f - m_) / Sp;
        bc[i] = m_ / Sg;
    }

    v4f accP = zero4, accG = zero4;
    const bf16* vrow = VhT + (long)(n * 512 + hd * 64 + wave * 16 + c) * 512 + quad * 8;
#pragma unroll
    for (int ks = 0; ks < 16; ++ks) {
        bfx8 bf_ = *(const bfx8*)(vrow + ks * 32);
        bfx8 ap = *(const bfx8*)(&Pp[c][ks * 32 + quad * 8]);
        bfx8 ag = *(const bfx8*)(&Pg[c][ks * 32 + quad * 8]);
        accP = mfma16(ap, bf_, accP);
        accG = mfma16(ag, bf_, accG);
    }

#pragma unroll
    for (int i = 0; i < 4; ++i) {
        int q = qt * 16 + quad * 4 + i;
        int cx = (wave * 16 + c) ^ (((quad * 4 + i) & 7) << 3);  // pre-swizzle for gemm128
        att[(long)(n * 512 + q) * 512 + hd * 64 + cx] =
            (bf16)(ac[i] * accP[i] + bc[i] * accG[i]);
    }
}

// ---------------------------------------------------------------------------
extern "C" void kernel_launch(void* const* d_in, const int* in_sizes, int n_in,
                              void* d_out, int out_size, void* d_ws, size_t ws_size,
                              hipStream_t stream) {
    (void)in_sizes; (void)n_in; (void)out_size; (void)ws_size;

    const float* Q = (const float*)d_in[0];
    const float* K = (const float*)d_in[1];
    const float* V = (const float*)d_in[2];
    const float* past_state = (const float*)d_in[3];
    const float* past_att = (const float*)d_in[4];
    const float* vpos = (const float*)d_in[5];
    const int* mask = (const int*)d_in[6];
    const float* Wq = (const float*)d_in[7];
    const float* Wk = (const float*)d_in[8];
    const float* Wv = (const float*)d_in[9];
    const float* Wpos = (const float*)d_in[10];
    const float* bpos = (const float*)d_in[11];
    const float* Wsigma = (const float*)d_in[12];
    const float* Wrho = (const float*)d_in[13];
    const float* mix_w = (const float*)d_in[14];
    const float* mix_b = (const float*)d_in[15];
    const float* gwi = (const float*)d_in[16];
    const float* gwh = (const float*)d_in[17];
    const float* gbi = (const float*)d_in[18];
    const float* gbh = (const float*)d_in[19];
    const float* Wc = (const float*)d_in[20];
    float* out = (float*)d_out;

    // ---- workspace ----
    char* p = (char*)d_ws;
    const size_t SZB = 8192UL * 512 * 2;
    const size_t SZW = 512UL * 512 * 2;
    bf16* WqT = (bf16*)p;   p += SZW;
    bf16* WkT = (bf16*)p;   p += SZW;
    bf16* WvT = (bf16*)p;   p += SZW;
    bf16* WpT = (bf16*)p;   p += SZW;
    bf16* WpTl = (bf16*)p;  p += SZW;
    bf16* WcT = (bf16*)p;   p += SZW;
    bf16* wih = (bf16*)p;   p += 24576;
    bf16* wil = (bf16*)p;   p += 24576;
    bf16* whh = (bf16*)p;   p += 24576;
    bf16* whl = (bf16*)p;   p += 24576;
    bf16* Qh = (bf16*)p;    p += SZB;
    bf16* Kh = (bf16*)p;    p += SZB;
    bf16* VhT = (bf16*)p;   p += SZB;
    bf16* Xh = (bf16*)p;
    bf16* att = Xh;         p += SZB;
    bf16* Xl = (bf16*)p;    p += SZB;
    unsigned* maskbits = (unsigned*)p;   p += 8192UL * 16 * 4;
    float* mixv = (float*)p;  p += 32768;
    float* stepv = (float*)p; p += 32768;
    float* lenv = (float*)p;  p += 32768;
    float* muv = (float*)p;   p += 262144;
    float* sigv = (float*)p;  p += 262144;

    dim3 blk(256);

    TW tw;
    tw.src[0] = Wq; tw.src[1] = Wk; tw.src[2] = Wv; tw.src[3] = Wpos; tw.src[4] = Wc;
    tw.dst[0] = WqT; tw.dst[1] = WkT; tw.dst[2] = WvT; tw.dst[3] = WpT; tw.dst[4] = WcT;
    tw.dstlo[0] = nullptr; tw.dstlo[1] = nullptr; tw.dstlo[2] = nullptr;
    tw.dstlo[3] = WpTl; tw.dstlo[4] = nullptr;
    trans_w_kernel<<<dim3(64, 5), blk, 0, stream>>>(tw);

    gru_prep_kernel<<<dim3(2), dim3(192), 0, stream>>>(gwi, gwh, wih, wil, whh, whl);

    mix_len_kernel<<<dim3(2048), blk, 0, stream>>>(Q, mask, mix_w, mix_b, mixv, stepv, lenv, maskbits);

    // projections: d[0]=split (longest, z=0 dispatched first), d[1]=Q, d[2]=K, d[3]=V(T)
    G4 gp;
    gp.d[0].Af = Q;  gp.d[0].Ab = nullptr; gp.d[0].B0 = WpT; gp.d[0].B1 = WpTl;
    gp.d[0].bias = bpos; gp.d[0].Cb = Xh; gp.d[0].Cl = Xl; gp.d[0].Cf = nullptr; gp.d[0].mode = 2;
    gp.d[1].Af = Q;  gp.d[1].Ab = nullptr; gp.d[1].B0 = WqT; gp.d[1].B1 = nullptr;
    gp.d[1].bias = nullptr; gp.d[1].Cb = Qh; gp.d[1].Cl = nullptr; gp.d[1].Cf = nullptr; gp.d[1].mode = 0;
    gp.d[2].Af = K;  gp.d[2].Ab = nullptr; gp.d[2].B0 = WkT; gp.d[2].B1 = nullptr;
    gp.d[2].bias = nullptr; gp.d[2].Cb = Kh; gp.d[2].Cl = nullptr; gp.d[2].Cf = nullptr; gp.d[2].mode = 0;
    gp.d[3].Af = V;  gp.d[3].Ab = nullptr; gp.d[3].B0 = WvT; gp.d[3].B1 = nullptr;
    gp.d[3].bias = nullptr; gp.d[3].Cb = VhT; gp.d[3].Cl = nullptr; gp.d[3].Cf = nullptr; gp.d[3].mode = 1;
    gemm128<<<dim3(64, 4, 4), blk, 0, stream>>>(gp);

    gru_fused_kernel<<<dim3(1024), blk, 0, stream>>>(
        Xh, Xl, past_state, wih, wil, whh, whl, gbi, gbh, past_att, Wsigma, Wrho,
        lenv, stepv, muv, sigv);

    attn_fused_kernel<<<dim3(4096), blk, 0, stream>>>(
        Qh, Kh, VhT, maskbits, vpos, mixv, stepv, muv, sigv, att);

    G4 go;
    go.d[0].Af = nullptr; go.d[0].Ab = att; go.d[0].B0 = WcT; go.d[0].B1 = nullptr;
    go.d[0].bias = nullptr; go.d[0].Cb = nullptr; go.d[0].Cl = nullptr; go.d[0].Cf = out;
    go.d[0].mode = 3;
    go.d[1] = go.d[0]; go.d[2] = go.d[0]; go.d[3] = go.d[0];  // unused
    gemm128<<<dim3(64, 4, 1), blk, 0, stream>>>(go);
}